// Round 1
// baseline (103.709 us; speedup 1.0000x reference)
//
#include <hip/hip_runtime.h>
#include <math.h>

// S4 Vandermonde kernel: K[h,l] = 2*Re( sum_n Ct[h,n] * exp(dtA[h,n])^l )
//   dt  = exp(log_dt)
//   A   = -exp(log_A_real) - i*A_imag
//   dtA = A*dt
//   Ct  = C * (exp(dtA)-1) / A        (complex)
//
// H=1024, NH=32, L=4096 (fixed by the harness).
//
// Strategy: one block per (h, 2048-wide l-tile). Per-(h,n) coefficients are
// computed once into LDS by lanes 0..31. Each thread owns 8 l-values strided
// by 256 (coalesced stores); per n it computes the starting z = exp(dtA*l)
// with one exp + one sincos, then advances with a complex-multiply recurrence
// z *= exp(dtA*256). Terms that have decayed below 2e-16 at the thread's
// first l are skipped entirely (exp decays monotonically in l).

#define HH 1024
#define NH 32
#define LL 4096
#define BLOCK 256
#define CHUNK 8
#define LTILE (BLOCK * CHUNK)      // 2048
#define NBLK_PER_H (LL / LTILE)    // 2

#define TWO_PI 6.28318530717958647692f
#define INV_TWO_PI 0.15915494309189533577f

__global__ __launch_bounds__(BLOCK) void s4_vandermonde(
    const float* __restrict__ C,            // [H][NH][2]
    const float* __restrict__ log_dt,       // [H]
    const float* __restrict__ log_A_real,   // [H][NH]
    const float* __restrict__ A_imag,       // [H][NH]
    float* __restrict__ out)                // [H][LL]
{
    __shared__ float sCtr[NH], sCti[NH], sRe[NH], sFm[NH], sWr[NH], sWi[NH];

    const int h  = blockIdx.x >> 1;              // NBLK_PER_H == 2
    const int l0 = (blockIdx.x & 1) * LTILE;
    const int t  = threadIdx.x;

    if (t < NH) {
        const int n = t;
        const float dt  = __expf(log_dt[h]);
        const float Are = -__expf(log_A_real[h * NH + n]);
        const float Aim = -A_imag[h * NH + n];
        const float re = Are * dt;               // Re(dtA)  (negative)
        const float im = Aim * dt;               // Im(dtA)
        // exp(dtA) - 1
        float s1, c1;
        __sincosf(im, &s1, &c1);
        const float er1 = __expf(re);
        const float X = er1 * c1 - 1.0f;
        const float Y = er1 * s1;
        // Ct = C * (exp(dtA)-1) / A, folded with the final factor of 2
        const float C0 = C[(h * NH + n) * 2 + 0];
        const float C1 = C[(h * NH + n) * 2 + 1];
        const float nr = C0 * X - C1 * Y;
        const float ni = C0 * Y + C1 * X;
        const float inv = 2.0f / (Are * Are + Aim * Aim);
        sCtr[n] = (nr * Are + ni * Aim) * inv;
        sCti[n] = (ni * Are - nr * Aim) * inv;
        sRe[n] = re;
        const float fm = im * INV_TWO_PI;        // revolutions per step
        sFm[n] = fm;
        // wstep = exp(dtA * BLOCK)   (stride-256 advance)
        const float reB = re * (float)BLOCK;
        const float erB = (reB < -80.0f) ? 0.0f : __expf(reB);
        float revB = fm * (float)BLOCK;
        revB -= floorf(revB);
        float sB, cB;
        __sincosf(revB * TWO_PI, &sB, &cB);
        sWr[n] = erB * cB;
        sWi[n] = erB * sB;
    }
    __syncthreads();

    float acc[CHUNK];
#pragma unroll
    for (int k = 0; k < CHUNK; ++k) acc[k] = 0.0f;

    const float lf = (float)(l0 + t);            // thread's first l

    for (int n = 0; n < NH; ++n) {
        const float re = sRe[n];
        const float a = re * lf;
        if (a < -36.0f) continue;                // exp < 2.3e-16, and only decays
        const float er = __expf(a);
        float rev = sFm[n] * lf;
        rev -= floorf(rev);
        float s, c;
        __sincosf(rev * TWO_PI, &s, &c);
        float zr = er * c;
        float zi = er * s;
        const float ctr = sCtr[n];
        const float cti = sCti[n];
        const float wr = sWr[n];
        const float wi = sWi[n];
#pragma unroll
        for (int k = 0; k < CHUNK; ++k) {
            acc[k] += ctr * zr - cti * zi;
            const float tr = zr * wr - zi * wi;
            zi = zr * wi + zi * wr;
            zr = tr;
        }
    }

    float* o = out + h * LL + l0 + t;
#pragma unroll
    for (int k = 0; k < CHUNK; ++k) o[k * BLOCK] = acc[k];
}

extern "C" void kernel_launch(void* const* d_in, const int* in_sizes, int n_in,
                              void* d_out, int out_size, void* d_ws, size_t ws_size,
                              hipStream_t stream) {
    const float* C          = (const float*)d_in[0];   // [1024][32][2]
    const float* log_dt     = (const float*)d_in[1];   // [1024]
    const float* log_A_real = (const float*)d_in[2];   // [1024][32]
    const float* A_imag     = (const float*)d_in[3];   // [1024][32]
    float* out              = (float*)d_out;           // [1024][4096]

    s4_vandermonde<<<dim3(HH * NBLK_PER_H), dim3(BLOCK), 0, stream>>>(
        C, log_dt, log_A_real, A_imag, out);
}

// Round 2
// 86.182 us; speedup vs baseline: 1.2034x; 1.2034x over previous
//
#include <hip/hip_runtime.h>
#include <math.h>

// S4 Vandermonde kernel: K[h,l] = 2*Re( sum_n Ct[h,n] * exp(dtA[h,n])^l )
//   dt  = exp(log_dt)
//   A   = -exp(log_A_real) - i*A_imag
//   dtA = A*dt
//   Ct  = C * (exp(dtA)-1) / A        (complex)
//
// H=1024, NH=32, L=4096 (fixed).
//
// Round-2 structure: 2 blocks per h; block b owns the INTERLEAVED l-chunks
// c = b, b+2, ..., b+14 (chunks of 256), so both sibling blocks carry equal
// low-l/high-l work (round-1 had half the grid idle: the l>=2048 block
// skipped nearly all n). Thread t's l-values are (b+2k)*256 + t, k=0..7;
// per n it computes z0 = exp(dtA*lf) (one exp + one sincos) and advances
// with z *= exp(dtA*512). A per-n wave-uniform kcap stops the recurrence
// once |z| < e^-40 (terms are monotonically decaying in l).

#define HH 1024
#define NH 32
#define LL 4096
#define BLOCK 256
#define CHUNK 8

#define TWO_PI 6.28318530717958647692f
#define INV_TWO_PI 0.15915494309189533577f

__global__ __launch_bounds__(BLOCK) void s4_vandermonde(
    const float* __restrict__ C,            // [H][NH][2]
    const float* __restrict__ log_dt,       // [H]
    const float* __restrict__ log_A_real,   // [H][NH]
    const float* __restrict__ A_imag,       // [H][NH]
    float* __restrict__ out)                // [H][LL]
{
    __shared__ float4 sA[NH];   // {ctr, cti, re, fm}
    __shared__ float4 sB[NH];   // {wr, wi, bitcast(kcap), unused}

    const int h = blockIdx.x >> 1;
    const int b = blockIdx.x & 1;
    const int t = threadIdx.x;

    if (t < NH) {
        const int n = t;
        const float dt  = __expf(log_dt[h]);
        const float Are = -__expf(log_A_real[h * NH + n]);
        const float Aim = -A_imag[h * NH + n];
        const float re = Are * dt;               // Re(dtA), negative
        const float im = Aim * dt;               // Im(dtA)
        // exp(dtA) - 1
        float s1, c1;
        __sincosf(im, &s1, &c1);
        const float er1 = __expf(re);
        const float X = er1 * c1 - 1.0f;
        const float Y = er1 * s1;
        // Ct = C * (exp(dtA)-1) / A, folded with the final factor of 2
        const float C0 = C[(h * NH + n) * 2 + 0];
        const float C1 = C[(h * NH + n) * 2 + 1];
        const float nr = C0 * X - C1 * Y;
        const float ni = C0 * Y + C1 * X;
        const float inv = 2.0f / (Are * Are + Aim * Aim);
        const float ctr = (nr * Are + ni * Aim) * inv;
        const float cti = (ni * Are - nr * Aim) * inv;
        const float fm = im * INV_TWO_PI;        // revolutions per unit l

        // wstep = exp(dtA * 512) with double-precision phase reduction
        const float reS = re * 512.0f;
        const float erS = (reS < -80.0f) ? 0.0f : __expf(reS);
        double revd = (double)fm * 512.0;
        revd -= floor(revd);
        float sS, cS;
        __sincosf((float)revd * TWO_PI, &sS, &cS);

        // kcap: number of k-steps before re*(512k) < -40 (k=0 always live)
        const float kl = -40.0f / (re * 512.0f);     // positive
        const int kcap = (kl >= 7.0f) ? 8 : ((int)kl + 1);

        sA[n] = make_float4(ctr, cti, re, fm);
        sB[n] = make_float4(erS * cS, erS * sS, __int_as_float(kcap), 0.0f);
    }
    __syncthreads();

    float acc[CHUNK];
#pragma unroll
    for (int k = 0; k < CHUNK; ++k) acc[k] = 0.0f;

    const float lf = (float)(b * 256 + t);       // thread's first l (<= 511)

    for (int n = 0; n < NH; ++n) {
        const float4 A4 = sA[n];
        const float a = A4.z * lf;
        if (a < -40.0f) continue;                // term < 4e-18 at first l
        const float4 B4 = sB[n];
        const float er = __expf(a);
        float rev = A4.w * lf;
        rev -= floorf(rev);
        float s, c;
        __sincosf(rev * TWO_PI, &s, &c);
        float zr = er * c;
        float zi = er * s;
        const int kcap = __float_as_int(B4.z);   // wave-uniform
#pragma unroll
        for (int k = 0; k < CHUNK; ++k) {
            if (k >= kcap) break;
            acc[k] += A4.x * zr - A4.y * zi;
            const float tr = zr * B4.x - zi * B4.y;
            zi = zr * B4.y + zi * B4.x;
            zr = tr;
        }
    }

    float* o = out + h * LL + b * 256 + t;
#pragma unroll
    for (int k = 0; k < CHUNK; ++k) o[k * 512] = acc[k];
}

extern "C" void kernel_launch(void* const* d_in, const int* in_sizes, int n_in,
                              void* d_out, int out_size, void* d_ws, size_t ws_size,
                              hipStream_t stream) {
    const float* C          = (const float*)d_in[0];   // [1024][32][2]
    const float* log_dt     = (const float*)d_in[1];   // [1024]
    const float* log_A_real = (const float*)d_in[2];   // [1024][32]
    const float* A_imag     = (const float*)d_in[3];   // [1024][32]
    float* out              = (float*)d_out;           // [1024][4096]

    s4_vandermonde<<<dim3(HH * 2), dim3(BLOCK), 0, stream>>>(
        C, log_dt, log_A_real, A_imag, out);
}